// Round 4
// baseline (186.570 us; speedup 1.0000x reference)
//
#include <hip/hip_runtime.h>
#include <math.h>

// EquiTritonModel: N=10000 nodes, E=160000 edges, D=32, H=16, NB=16.
// R17 -> R18: edge_kernel proved atomic-RATE-bound: 20.5M fp32 atomic
// dwords = 80 MB WRITE_SIZE at ~295 G ops/s => 69us. Halved the storm:
//   K1 table_kernel: TI table + zero zacc (2.6 MB) + zero out
//   K2 edge_kernel : z-side only (4 atomics/lane-edge = 10.2M ops);
//                    readout term folded in algebraically
//                    (sum_n 0.25*z0.r == 0.25*K0 * sum_e u0.r)
//   K3 edge2_kernel: recompute geometry+h1; gather RAW zacc[src]
//                    (4 x 64B, L2-resident); per-lane-ROW G-transform:
//                    c3 = sum_h z0[h]*H1[h] + (u.zvec[h])*H4[h],
//                    H1[h] = sum_t G1[h,t]*h1[t] -> only 16 shuffles/edge.
// sacc, QP, node_kernel all deleted. Still 3 dispatches.

namespace {
constexpr int   NATOMS   = 100;
constexpr float PI_F     = 3.14159265358979323846f;
constexpr float INV4PI_F = 0.28209479177387814f;   // 1/sqrt(4*pi)
constexpr float SQRT3_F  = 1.7320508075688772f;
constexpr float CUT_F    = 6.0f;
constexpr float BASIS_C  = 2.3094010767585034f;    // sqrt(2/6)*sqrt(16)
constexpr float N0_F     = 0.17677669529663687f;   // 1/sqrt(32)
constexpr float K0_F = INV4PI_F * N0_F * 0.0625f;  // z0 scale incl /DEG
constexpr float K1_F = SQRT3_F * INV4PI_F * N0_F * 0.0625f;
constexpr float P2SC = INV4PI_F * N0_F * (1.0f / 64.0f);
}

__device__ __forceinline__ float silu_fast(float x) {
  return x / (1.0f + __expf(-x));
}

__device__ __forceinline__ float block_reduce_sum(float v) {
  #pragma unroll
  for (int o = 32; o > 0; o >>= 1) v += __shfl_down(v, o, 64);
  __shared__ float ls[8];
  int lane = threadIdx.x & 63;
  int w    = threadIdx.x >> 6;
  if (lane == 0) ls[w] = v;
  __syncthreads();
  float s = 0.f;
  if (threadIdx.x == 0) {
    int nw = (blockDim.x + 63) >> 6;
    for (int i = 0; i < nw; ++i) s += ls[i];
  }
  return s;
}

// ---------------------------------------------------------------------------
// table_kernel: blocks [0,NATOMS) -> TI tables; blocks >= NATOMS zero zacc
// (N*64 floats as float4) — no hipMemset needed.
// ---------------------------------------------------------------------------
__global__ void __launch_bounds__(256)
table_kernel(const float* __restrict__ atom_emb,
             const float* __restrict__ fc0_w2,
             float* __restrict__ TI,
             float4* __restrict__ zero4,   // zacc as float4
             float* __restrict__ out,
             int NZ4) {
  int b = blockIdx.x;
  int tt = threadIdx.x;
  if (b < NATOMS) {
    int j = tt >> 4;
    int h = tt & 15;
    float s0 = 0.f, s1 = 0.f;
    #pragma unroll
    for (int d = 0; d < 32; ++d) {
      float x = atom_emb[b * 32 + d];
      s0 = fmaf(x, fc0_w2[j * 1024 + d * 16 + h], s0);
      s1 = fmaf(x, fc0_w2[j * 1024 + 512 + d * 16 + h], s1);
    }
    TI[b * 512 + j * 32 + 2 * h]     = s0;
    TI[b * 512 + j * 32 + 2 * h + 1] = s1;
    if (b == 0 && tt == 0) *out = 0.f;
  } else {
    int idx = (b - NATOMS) * 256 + tt;
    if (idx < NZ4) zero4[idx] = make_float4(0.f, 0.f, 0.f, 0.f);
  }
}

// ---------------------------------------------------------------------------
// edge_kernel: 16 groups x 16 lanes; group g handles edges b*32+g and
// b*32+16+g (2-edge ILP pipeline). z-side atomics only (fire-and-forget):
//   zacc[dst*64 + {t,16+t,32+t,48+t}] += {K0*u0, K1*u1*ux/uy/uz}
// Readout term accumulated in-register: c += 0.25*K0*u0[t]*r[t].
// ---------------------------------------------------------------------------
__global__ void __launch_bounds__(256)
edge_kernel(const int* __restrict__ ei,
            const float* __restrict__ coords,
            const int* __restrict__ an,
            const float* __restrict__ TI,
            const float* __restrict__ fc0_w1,
            const float* __restrict__ w_readout,
            float* __restrict__ zacc,
            float* __restrict__ out,
            int E) {
  int lane = threadIdx.x & 63;
  int g    = threadIdx.x >> 4;       // block group 0..15
  int t    = threadIdx.x & 15;
  int base = lane & 48;

  float w0c[16];
  #pragma unroll
  for (int k = 0; k < 16; ++k) w0c[k] = fc0_w1[k * 16 + t];
  float rr = w_readout[t];

  const float angc = PI_F / CUT_F;
  int eA = blockIdx.x * 32 + g;
  int eB = eA + 16;
  bool vA = eA < E, vB = eB < E;
  int eAc = vA ? eA : 0, eBc = vB ? eB : 0;

  // ---- phase 1: all input loads ----
  int sA = ei[eAc], dA = ei[E + eAc];
  int sB = ei[eBc], dB = ei[E + eBc];
  float sxA = coords[3 * sA + 0], syA = coords[3 * sA + 1], szA = coords[3 * sA + 2];
  float dxA = coords[3 * dA + 0], dyA = coords[3 * dA + 1], dzA = coords[3 * dA + 2];
  float sxB = coords[3 * sB + 0], syB = coords[3 * sB + 1], szB = coords[3 * sB + 2];
  float dxB = coords[3 * dB + 0], dyB = coords[3 * dB + 1], dzB = coords[3 * dB + 2];
  int aA = an[sA], aB = an[sB];

  // ---- phase 2: geometry ----
  float vxA = sxA - dxA, vyA = syA - dyA, vzA = szA - dzA;
  float vxB = sxB - dxB, vyB = syB - dyB, vzB = szB - dzB;
  float distA = sqrtf(vxA * vxA + vyA * vyA + vzA * vzA);
  float distB = sqrtf(vxB * vxB + vyB * vyB + vzB * vzB);
  float ivA = 1.0f / fmaxf(distA, 1e-9f);
  float ivB = 1.0f / fmaxf(distB, 1e-9f);
  float uxA = vxA * ivA, uyA = vyA * ivA, uzA = vzA * ivA;
  float uxB = vxB * ivB, uyB = vyB * ivB, uzB = vzB * ivB;
  float bcA = (distA < CUT_F) ? (BASIS_C * ivA) : 0.0f;
  float bcB = (distB < CUT_F) ? (BASIS_C * ivB) : 0.0f;

  // ---- phase 3: interleaved sine recurrences (h0 only) ----
  float angA = angc * distA, angB = angc * distB;
  float scA = __sinf(angA), twA = 2.0f * __cosf(angA), spA = 0.f;
  float scB = __sinf(angB), twB = 2.0f * __cosf(angB), spB = 0.f;
  float a0A = 0.f, a0B = 0.f;
  #pragma unroll
  for (int k = 0; k < 16; ++k) {
    a0A = fmaf(scA, w0c[k], a0A);
    a0B = fmaf(scB, w0c[k], a0B);
    float snA = fmaf(twA, scA, -spA); spA = scA; scA = snA;
    float snB = fmaf(twB, scB, -spB); spB = scB; scB = snB;
  }
  float h0A = silu_fast(a0A * bcA * 0.25f);
  float h0B = silu_fast(a0B * bcB * 0.25f);

  // ---- phase 4: interleaved TI loads + contraction ----
  const float2* tpA = (const float2*)(TI + aA * 512) + t;
  const float2* tpB = (const float2*)(TI + aB * 512) + t;
  float u0A = 0.f, u1A = 0.f, u0B = 0.f, u1B = 0.f;
  #pragma unroll
  for (int j = 0; j < 16; ++j) {
    float hjA = __shfl(h0A, base + j, 64);
    float hjB = __shfl(h0B, base + j, 64);
    float2 TA = tpA[j * 16];
    float2 TB = tpB[j * 16];
    u0A = fmaf(hjA, TA.x, u0A);
    u1A = fmaf(hjA, TA.y, u1A);
    u0B = fmaf(hjB, TB.x, u0B);
    u1B = fmaf(hjB, TB.y, u1B);
  }

  // ---- phase 5: z-side atomics + readout accumulation ----
  float c = 0.f;
  if (vA) {
    float* za = zacc + (size_t)dA * 64 + t;
    float m1 = K1_F * u1A;
    unsafeAtomicAdd(za,      K0_F * u0A);
    unsafeAtomicAdd(za + 16, m1 * uxA);
    unsafeAtomicAdd(za + 32, m1 * uyA);
    unsafeAtomicAdd(za + 48, m1 * uzA);
    c = fmaf(u0A, rr, c);
  }
  if (vB) {
    float* zb = zacc + (size_t)dB * 64 + t;
    float m1 = K1_F * u1B;
    unsafeAtomicAdd(zb,      K0_F * u0B);
    unsafeAtomicAdd(zb + 16, m1 * uxB);
    unsafeAtomicAdd(zb + 32, m1 * uyB);
    unsafeAtomicAdd(zb + 48, m1 * uzB);
    c = fmaf(u0B, rr, c);
  }
  c *= 0.25f * K0_F;

  float tot = block_reduce_sum(c);
  if (threadIdx.x == 0) atomicAdd(out, tot);
}

// ---------------------------------------------------------------------------
// edge2_kernel: grid-stride 2-edge pipeline. Per edge: recompute geometry +
// h1 recurrence; gather raw zacc[src] (4 x 64B); row-form G-transform:
//   H1[h] = sum_t G1[h,t]*h1[t]  (16 shuffles + 32 FMA, lane h holds row h)
//   c3 += z0[h]*H1[h] + (u . zvec[h]) * H4[h]
// ---------------------------------------------------------------------------
__global__ void __launch_bounds__(256)
edge2_kernel(const int* __restrict__ ei,
             const float* __restrict__ coords,
             const float* __restrict__ zacc,
             const float* __restrict__ fc1_w1,
             const float* __restrict__ fc1_w2,
             const float* __restrict__ w_readout,
             float* __restrict__ out,
             int E) {
  __shared__ float ggs[512];          // [0:256)=G1 rows, [256:512)=G4 rows
  {
    int j = threadIdx.x >> 4;         // hidden index
    int h = threadIdx.x & 15;
    float g1 = 0.f, g4 = 0.f;
    #pragma unroll
    for (int k = 0; k < 16; ++k) {
      float r = w_readout[k];
      g1 = fmaf(fc1_w2[j * 1024 + h * 16 + k], r, g1);
      g4 = fmaf(fc1_w2[j * 1024 + 768 + h * 16 + k], r, g4);
    }
    ggs[h * 16 + j]       = g1;       // G1[h, t=j]
    ggs[256 + h * 16 + j] = g4;       // G4[h, t=j]
  }
  __syncthreads();

  int lane = threadIdx.x & 63;
  int t    = lane & 15;               // this lane's h-row
  int base = lane & 48;

  // per-lane register row of G1/G4 and recurrence weights
  float g1r[16], g4r[16], w1c[16];
  #pragma unroll
  for (int k = 0; k < 16; ++k) {
    g1r[k] = ggs[t * 16 + k];
    g4r[k] = ggs[256 + t * 16 + k];
    w1c[k] = fc1_w1[k * 16 + t];
  }

  const float angc = PI_F / CUT_F;
  int ggid = blockIdx.x * 16 + (threadIdx.x >> 4);
  int ngroups = gridDim.x * 16;

  float c3 = 0.f;
  for (int e0 = ggid; e0 < E; e0 += 2 * ngroups) {
    int eA = e0;
    int eB = e0 + ngroups;
    bool vB = eB < E;
    int eBc = vB ? eB : eA;

    int sA = ei[eA],  dA = ei[E + eA];
    int sB = ei[eBc], dB = ei[E + eBc];
    float sxA = coords[3 * sA + 0], syA = coords[3 * sA + 1], szA = coords[3 * sA + 2];
    float dxA = coords[3 * dA + 0], dyA = coords[3 * dA + 1], dzA = coords[3 * dA + 2];
    float sxB = coords[3 * sB + 0], syB = coords[3 * sB + 1], szB = coords[3 * sB + 2];
    float dxB = coords[3 * dB + 0], dyB = coords[3 * dB + 1], dzB = coords[3 * dB + 2];

    // z gathers issued early (independent of geometry)
    size_t qa = (size_t)sA * 64;
    size_t qb = (size_t)sB * 64;
    float z0A = zacc[qa + t],      z0B = zacc[qb + t];
    float zxA = zacc[qa + 16 + t], zxB = zacc[qb + 16 + t];
    float zyA = zacc[qa + 32 + t], zyB = zacc[qb + 32 + t];
    float zzA = zacc[qa + 48 + t], zzB = zacc[qb + 48 + t];

    float vxA = sxA - dxA, vyA = syA - dyA, vzA = szA - dzA;
    float vxB = sxB - dxB, vyB = syB - dyB, vzB = szB - dzB;
    float distA = sqrtf(vxA * vxA + vyA * vyA + vzA * vzA);
    float distB = sqrtf(vxB * vxB + vyB * vyB + vzB * vzB);
    float ivA = 1.0f / fmaxf(distA, 1e-9f);
    float ivB = 1.0f / fmaxf(distB, 1e-9f);
    float uxA = vxA * ivA, uyA = vyA * ivA, uzA = vzA * ivA;
    float uxB = vxB * ivB, uyB = vyB * ivB, uzB = vzB * ivB;
    float bcA = (distA < CUT_F) ? (BASIS_C * ivA) : 0.0f;
    float bcB = (distB < CUT_F) ? (BASIS_C * ivB) : 0.0f;

    float angA = angc * distA, angB = angc * distB;
    float scA = __sinf(angA), twA = 2.0f * __cosf(angA), spA = 0.f;
    float scB = __sinf(angB), twB = 2.0f * __cosf(angB), spB = 0.f;
    float a1A = 0.f, a1B = 0.f;
    #pragma unroll
    for (int k = 0; k < 16; ++k) {
      a1A = fmaf(scA, w1c[k], a1A);
      a1B = fmaf(scB, w1c[k], a1B);
      float snA = fmaf(twA, scA, -spA); spA = scA; scA = snA;
      float snB = fmaf(twB, scB, -spB); spB = scB; scB = snB;
    }
    float h1A = silu_fast(a1A * bcA * 0.25f);
    float h1B = silu_fast(a1B * bcB * 0.25f);

    // row-form transform: 16 shuffles + 32 FMA per edge
    float H1A = 0.f, H4A = 0.f, H1B = 0.f, H4B = 0.f;
    #pragma unroll
    for (int k = 0; k < 16; ++k) {
      float hbA = __shfl(h1A, base + k, 64);
      float hbB = __shfl(h1B, base + k, 64);
      H1A = fmaf(g1r[k], hbA, H1A);
      H4A = fmaf(g4r[k], hbA, H4A);
      H1B = fmaf(g1r[k], hbB, H1B);
      H4B = fmaf(g4r[k], hbB, H4B);
    }

    float wA = fmaf(uxA, zxA, fmaf(uyA, zyA, uzA * zzA));
    float wB = fmaf(uxB, zxB, fmaf(uyB, zyB, uzB * zzB));
    c3 = fmaf(H1A, z0A, fmaf(H4A, wA, c3));
    if (vB) c3 = fmaf(H1B, z0B, fmaf(H4B, wB, c3));
  }

  float tot = block_reduce_sum(c3 * P2SC);
  if (threadIdx.x == 0) atomicAdd(out, tot);
}

extern "C" void kernel_launch(void* const* d_in, const int* in_sizes, int n_in,
                              void* d_out, int out_size, void* d_ws, size_t ws_size,
                              hipStream_t stream) {
  const int*   an        = (const int*)d_in[0];
  const float* coords    = (const float*)d_in[1];
  const int*   ei        = (const int*)d_in[2];
  const float* atom_emb  = (const float*)d_in[3];
  const float* fc0_w1    = (const float*)d_in[4];
  const float* fc0_w2    = (const float*)d_in[5];
  const float* fc1_w1    = (const float*)d_in[6];
  const float* fc1_w2    = (const float*)d_in[7];
  const float* w_readout = (const float*)d_in[8];

  int N = in_sizes[0];
  int E = in_sizes[2] / 2;

  // ws layout (16B-aligned)
  float* zacc = (float*)d_ws;                   // N*64   (2.6 MB)
  float* TI   = zacc + (size_t)N * 64;          // 100*512
  float* out  = (float*)d_out;

  int NZ4 = N * 16;                             // zacc as float4
  int zblocks = (NZ4 + 255) / 256;
  table_kernel<<<NATOMS + zblocks, 256, 0, stream>>>(
      atom_emb, fc0_w2, TI, (float4*)zacc, out, NZ4);

  edge_kernel<<<(E + 31) / 32, 256, 0, stream>>>(
      ei, coords, an, TI, fc0_w1, w_readout, zacc, out, E);

  edge2_kernel<<<2048, 256, 0, stream>>>(
      ei, coords, zacc, fc1_w1, fc1_w2, w_readout, out, E);
}

// Round 6
// 148.448 us; speedup vs baseline: 1.2568x; 1.2568x over previous
//
#include <hip/hip_runtime.h>
#include <math.h>

// EquiTritonModel: N=10000 nodes, E=160000 edges, D=32, H=16, NB=16.
// R18 -> R19 (resubmit; R5 bench was an infra failure, kernel never ran).
// R18's regression (69->80us at HALF the atomic traffic) was
// self-inflicted: the readout fold added block_reduce_sum AFTER the
// fire-and-forget atomics; __syncthreads forces s_waitcnt vmcnt(0), so
// every block drained its atomics before exit (fire-and-WAIT), plus 5000
// same-address atomicAdd(out). Fix:
//   K2 edge_kernel : pure fire-and-forget again — no LDS, no barrier,
//                    no out atomic. Only the 4 z-side atomics/lane-edge.
//   K3 edge2_kernel: readout term computed here instead, as a grid-stride
//                    node sum over L2-resident zacc z0 rows (~1us),
//                    folded into the existing block reduce.
// Kernel-sum is the lever (fixed ~60us/iter overhead regardless of
// dispatch count, observed R15/R17/R18).

namespace {
constexpr int   NATOMS   = 100;
constexpr float PI_F     = 3.14159265358979323846f;
constexpr float INV4PI_F = 0.28209479177387814f;   // 1/sqrt(4*pi)
constexpr float SQRT3_F  = 1.7320508075688772f;
constexpr float CUT_F    = 6.0f;
constexpr float BASIS_C  = 2.3094010767585034f;    // sqrt(2/6)*sqrt(16)
constexpr float N0_F     = 0.17677669529663687f;   // 1/sqrt(32)
constexpr float K0_F = INV4PI_F * N0_F * 0.0625f;  // z0 scale incl /DEG
constexpr float K1_F = SQRT3_F * INV4PI_F * N0_F * 0.0625f;
constexpr float P2SC = INV4PI_F * N0_F * (1.0f / 64.0f);
}

__device__ __forceinline__ float silu_fast(float x) {
  return x / (1.0f + __expf(-x));
}

__device__ __forceinline__ float block_reduce_sum(float v) {
  #pragma unroll
  for (int o = 32; o > 0; o >>= 1) v += __shfl_down(v, o, 64);
  __shared__ float ls[8];
  int lane = threadIdx.x & 63;
  int w    = threadIdx.x >> 6;
  if (lane == 0) ls[w] = v;
  __syncthreads();
  float s = 0.f;
  if (threadIdx.x == 0) {
    int nw = (blockDim.x + 63) >> 6;
    for (int i = 0; i < nw; ++i) s += ls[i];
  }
  return s;
}

// ---------------------------------------------------------------------------
// table_kernel: blocks [0,NATOMS) -> TI tables; blocks >= NATOMS zero zacc
// (N*64 floats as float4) — no hipMemset needed.
// ---------------------------------------------------------------------------
__global__ void __launch_bounds__(256)
table_kernel(const float* __restrict__ atom_emb,
             const float* __restrict__ fc0_w2,
             float* __restrict__ TI,
             float4* __restrict__ zero4,   // zacc as float4
             float* __restrict__ out,
             int NZ4) {
  int b = blockIdx.x;
  int tt = threadIdx.x;
  if (b < NATOMS) {
    int j = tt >> 4;
    int h = tt & 15;
    float s0 = 0.f, s1 = 0.f;
    #pragma unroll
    for (int d = 0; d < 32; ++d) {
      float x = atom_emb[b * 32 + d];
      s0 = fmaf(x, fc0_w2[j * 1024 + d * 16 + h], s0);
      s1 = fmaf(x, fc0_w2[j * 1024 + 512 + d * 16 + h], s1);
    }
    TI[b * 512 + j * 32 + 2 * h]     = s0;
    TI[b * 512 + j * 32 + 2 * h + 1] = s1;
    if (b == 0 && tt == 0) *out = 0.f;
  } else {
    int idx = (b - NATOMS) * 256 + tt;
    if (idx < NZ4) zero4[idx] = make_float4(0.f, 0.f, 0.f, 0.f);
  }
}

// ---------------------------------------------------------------------------
// edge_kernel: 16 groups x 16 lanes; group g handles edges b*32+g and
// b*32+16+g (2-edge ILP pipeline). PURE fire-and-forget output:
//   zacc[dst*64 + {t,16+t,32+t,48+t}] += {K0*u0, K1*u1*ux/uy/uz}
// No LDS, no __syncthreads, no out atomic => no vmcnt(0) drain inside the
// kernel body; atomics retire during the dispatch tail.
// ---------------------------------------------------------------------------
__global__ void __launch_bounds__(256)
edge_kernel(const int* __restrict__ ei,
            const float* __restrict__ coords,
            const int* __restrict__ an,
            const float* __restrict__ TI,
            const float* __restrict__ fc0_w1,
            float* __restrict__ zacc,
            int E) {
  int lane = threadIdx.x & 63;
  int g    = threadIdx.x >> 4;       // block group 0..15
  int t    = threadIdx.x & 15;
  int base = lane & 48;

  float w0c[16];
  #pragma unroll
  for (int k = 0; k < 16; ++k) w0c[k] = fc0_w1[k * 16 + t];

  const float angc = PI_F / CUT_F;
  int eA = blockIdx.x * 32 + g;
  int eB = eA + 16;
  bool vA = eA < E, vB = eB < E;
  int eAc = vA ? eA : 0, eBc = vB ? eB : 0;

  // ---- phase 1: all input loads ----
  int sA = ei[eAc], dA = ei[E + eAc];
  int sB = ei[eBc], dB = ei[E + eBc];
  float sxA = coords[3 * sA + 0], syA = coords[3 * sA + 1], szA = coords[3 * sA + 2];
  float dxA = coords[3 * dA + 0], dyA = coords[3 * dA + 1], dzA = coords[3 * dA + 2];
  float sxB = coords[3 * sB + 0], syB = coords[3 * sB + 1], szB = coords[3 * sB + 2];
  float dxB = coords[3 * dB + 0], dyB = coords[3 * dB + 1], dzB = coords[3 * dB + 2];
  int aA = an[sA], aB = an[sB];

  // ---- phase 2: geometry ----
  float vxA = sxA - dxA, vyA = syA - dyA, vzA = szA - dzA;
  float vxB = sxB - dxB, vyB = syB - dyB, vzB = szB - dzB;
  float distA = sqrtf(vxA * vxA + vyA * vyA + vzA * vzA);
  float distB = sqrtf(vxB * vxB + vyB * vyB + vzB * vzB);
  float ivA = 1.0f / fmaxf(distA, 1e-9f);
  float ivB = 1.0f / fmaxf(distB, 1e-9f);
  float uxA = vxA * ivA, uyA = vyA * ivA, uzA = vzA * ivA;
  float uxB = vxB * ivB, uyB = vyB * ivB, uzB = vzB * ivB;
  float bcA = (distA < CUT_F) ? (BASIS_C * ivA) : 0.0f;
  float bcB = (distB < CUT_F) ? (BASIS_C * ivB) : 0.0f;

  // ---- phase 3: interleaved sine recurrences (h0 only) ----
  float angA = angc * distA, angB = angc * distB;
  float scA = __sinf(angA), twA = 2.0f * __cosf(angA), spA = 0.f;
  float scB = __sinf(angB), twB = 2.0f * __cosf(angB), spB = 0.f;
  float a0A = 0.f, a0B = 0.f;
  #pragma unroll
  for (int k = 0; k < 16; ++k) {
    a0A = fmaf(scA, w0c[k], a0A);
    a0B = fmaf(scB, w0c[k], a0B);
    float snA = fmaf(twA, scA, -spA); spA = scA; scA = snA;
    float snB = fmaf(twB, scB, -spB); spB = scB; scB = snB;
  }
  float h0A = silu_fast(a0A * bcA * 0.25f);
  float h0B = silu_fast(a0B * bcB * 0.25f);

  // ---- phase 4: interleaved TI loads + contraction ----
  const float2* tpA = (const float2*)(TI + aA * 512) + t;
  const float2* tpB = (const float2*)(TI + aB * 512) + t;
  float u0A = 0.f, u1A = 0.f, u0B = 0.f, u1B = 0.f;
  #pragma unroll
  for (int j = 0; j < 16; ++j) {
    float hjA = __shfl(h0A, base + j, 64);
    float hjB = __shfl(h0B, base + j, 64);
    float2 TA = tpA[j * 16];
    float2 TB = tpB[j * 16];
    u0A = fmaf(hjA, TA.x, u0A);
    u1A = fmaf(hjA, TA.y, u1A);
    u0B = fmaf(hjB, TB.x, u0B);
    u1B = fmaf(hjB, TB.y, u1B);
  }

  // ---- phase 5: z-side atomics (fire-and-forget) ----
  if (vA) {
    float* za = zacc + (size_t)dA * 64 + t;
    float m1 = K1_F * u1A;
    unsafeAtomicAdd(za,      K0_F * u0A);
    unsafeAtomicAdd(za + 16, m1 * uxA);
    unsafeAtomicAdd(za + 32, m1 * uyA);
    unsafeAtomicAdd(za + 48, m1 * uzA);
  }
  if (vB) {
    float* zb = zacc + (size_t)dB * 64 + t;
    float m1 = K1_F * u1B;
    unsafeAtomicAdd(zb,      K0_F * u0B);
    unsafeAtomicAdd(zb + 16, m1 * uxB);
    unsafeAtomicAdd(zb + 32, m1 * uyB);
    unsafeAtomicAdd(zb + 48, m1 * uzB);
  }
}

// ---------------------------------------------------------------------------
// edge2_kernel: grid-stride 2-edge pipeline. Per edge: recompute geometry +
// h1 recurrence; gather raw zacc[src] (4 x 64B); row-form G-transform:
//   H1[h] = sum_t G1[h,t]*h1[t]  (16 shuffles + 32 FMA, lane h holds row h)
//   c3 += z0[h]*H1[h] + (u . zvec[h]) * H4[h]
// Plus the readout term as a grid-stride node sum over zacc z0 rows:
//   cr = sum_n z0[n][t]  ->  contributes 0.25*rr*cr.
// ---------------------------------------------------------------------------
__global__ void __launch_bounds__(256)
edge2_kernel(const int* __restrict__ ei,
             const float* __restrict__ coords,
             const float* __restrict__ zacc,
             const float* __restrict__ fc1_w1,
             const float* __restrict__ fc1_w2,
             const float* __restrict__ w_readout,
             float* __restrict__ out,
             int N, int E) {
  __shared__ float ggs[512];          // [0:256)=G1 rows, [256:512)=G4 rows
  {
    int j = threadIdx.x >> 4;         // hidden index
    int h = threadIdx.x & 15;
    float g1 = 0.f, g4 = 0.f;
    #pragma unroll
    for (int k = 0; k < 16; ++k) {
      float r = w_readout[k];
      g1 = fmaf(fc1_w2[j * 1024 + h * 16 + k], r, g1);
      g4 = fmaf(fc1_w2[j * 1024 + 768 + h * 16 + k], r, g4);
    }
    ggs[h * 16 + j]       = g1;       // G1[h, t=j]
    ggs[256 + h * 16 + j] = g4;       // G4[h, t=j]
  }
  __syncthreads();

  int lane = threadIdx.x & 63;
  int t    = lane & 15;               // this lane's h-row
  int base = lane & 48;

  // per-lane register row of G1/G4 and recurrence weights
  float g1r[16], g4r[16], w1c[16];
  #pragma unroll
  for (int k = 0; k < 16; ++k) {
    g1r[k] = ggs[t * 16 + k];
    g4r[k] = ggs[256 + t * 16 + k];
    w1c[k] = fc1_w1[k * 16 + t];
  }
  float rr = w_readout[t];

  const float angc = PI_F / CUT_F;
  int ggid = blockIdx.x * 16 + (threadIdx.x >> 4);
  int ngroups = gridDim.x * 16;

  // ---- readout term: sum over nodes of z0 row (L2-resident) ----
  float cr = 0.f;
  for (int n = ggid; n < N; n += ngroups) {
    cr += zacc[(size_t)n * 64 + t];
  }

  // ---- main edge sweep ----
  float c3 = 0.f;
  for (int e0 = ggid; e0 < E; e0 += 2 * ngroups) {
    int eA = e0;
    int eB = e0 + ngroups;
    bool vB = eB < E;
    int eBc = vB ? eB : eA;

    int sA = ei[eA],  dA = ei[E + eA];
    int sB = ei[eBc], dB = ei[E + eBc];
    float sxA = coords[3 * sA + 0], syA = coords[3 * sA + 1], szA = coords[3 * sA + 2];
    float dxA = coords[3 * dA + 0], dyA = coords[3 * dA + 1], dzA = coords[3 * dA + 2];
    float sxB = coords[3 * sB + 0], syB = coords[3 * sB + 1], szB = coords[3 * sB + 2];
    float dxB = coords[3 * dB + 0], dyB = coords[3 * dB + 1], dzB = coords[3 * dB + 2];

    // z gathers issued early (independent of geometry)
    size_t qa = (size_t)sA * 64;
    size_t qb = (size_t)sB * 64;
    float z0A = zacc[qa + t],      z0B = zacc[qb + t];
    float zxA = zacc[qa + 16 + t], zxB = zacc[qb + 16 + t];
    float zyA = zacc[qa + 32 + t], zyB = zacc[qb + 32 + t];
    float zzA = zacc[qa + 48 + t], zzB = zacc[qb + 48 + t];

    float vxA = sxA - dxA, vyA = syA - dyA, vzA = szA - dzA;
    float vxB = sxB - dxB, vyB = syB - dyB, vzB = szB - dzB;
    float distA = sqrtf(vxA * vxA + vyA * vyA + vzA * vzA);
    float distB = sqrtf(vxB * vxB + vyB * vyB + vzB * vzB);
    float ivA = 1.0f / fmaxf(distA, 1e-9f);
    float ivB = 1.0f / fmaxf(distB, 1e-9f);
    float uxA = vxA * ivA, uyA = vyA * ivA, uzA = vzA * ivA;
    float uxB = vxB * ivB, uyB = vyB * ivB, uzB = vzB * ivB;
    float bcA = (distA < CUT_F) ? (BASIS_C * ivA) : 0.0f;
    float bcB = (distB < CUT_F) ? (BASIS_C * ivB) : 0.0f;

    float angA = angc * distA, angB = angc * distB;
    float scA = __sinf(angA), twA = 2.0f * __cosf(angA), spA = 0.f;
    float scB = __sinf(angB), twB = 2.0f * __cosf(angB), spB = 0.f;
    float a1A = 0.f, a1B = 0.f;
    #pragma unroll
    for (int k = 0; k < 16; ++k) {
      a1A = fmaf(scA, w1c[k], a1A);
      a1B = fmaf(scB, w1c[k], a1B);
      float snA = fmaf(twA, scA, -spA); spA = scA; scA = snA;
      float snB = fmaf(twB, scB, -spB); spB = scB; scB = snB;
    }
    float h1A = silu_fast(a1A * bcA * 0.25f);
    float h1B = silu_fast(a1B * bcB * 0.25f);

    // row-form transform: 16 shuffles + 32 FMA per edge
    float H1A = 0.f, H4A = 0.f, H1B = 0.f, H4B = 0.f;
    #pragma unroll
    for (int k = 0; k < 16; ++k) {
      float hbA = __shfl(h1A, base + k, 64);
      float hbB = __shfl(h1B, base + k, 64);
      H1A = fmaf(g1r[k], hbA, H1A);
      H4A = fmaf(g4r[k], hbA, H4A);
      H1B = fmaf(g1r[k], hbB, H1B);
      H4B = fmaf(g4r[k], hbB, H4B);
    }

    float wA = fmaf(uxA, zxA, fmaf(uyA, zyA, uzA * zzA));
    float wB = fmaf(uxB, zxB, fmaf(uyB, zyB, uzB * zzB));
    c3 = fmaf(H1A, z0A, fmaf(H4A, wA, c3));
    if (vB) c3 = fmaf(H1B, z0B, fmaf(H4B, wB, c3));
  }

  float tot = block_reduce_sum(fmaf(c3, P2SC, 0.25f * rr * cr));
  if (threadIdx.x == 0) atomicAdd(out, tot);
}

extern "C" void kernel_launch(void* const* d_in, const int* in_sizes, int n_in,
                              void* d_out, int out_size, void* d_ws, size_t ws_size,
                              hipStream_t stream) {
  const int*   an        = (const int*)d_in[0];
  const float* coords    = (const float*)d_in[1];
  const int*   ei        = (const int*)d_in[2];
  const float* atom_emb  = (const float*)d_in[3];
  const float* fc0_w1    = (const float*)d_in[4];
  const float* fc0_w2    = (const float*)d_in[5];
  const float* fc1_w1    = (const float*)d_in[6];
  const float* fc1_w2    = (const float*)d_in[7];
  const float* w_readout = (const float*)d_in[8];

  int N = in_sizes[0];
  int E = in_sizes[2] / 2;

  // ws layout (16B-aligned)
  float* zacc = (float*)d_ws;                   // N*64   (2.6 MB)
  float* TI   = zacc + (size_t)N * 64;          // 100*512
  float* out  = (float*)d_out;

  int NZ4 = N * 16;                             // zacc as float4
  int zblocks = (NZ4 + 255) / 256;
  table_kernel<<<NATOMS + zblocks, 256, 0, stream>>>(
      atom_emb, fc0_w2, TI, (float4*)zacc, out, NZ4);

  edge_kernel<<<(E + 31) / 32, 256, 0, stream>>>(
      ei, coords, an, TI, fc0_w1, zacc, E);

  edge2_kernel<<<2048, 256, 0, stream>>>(
      ei, coords, zacc, fc1_w1, fc1_w2, w_readout, out, N, E);
}